// Round 4
// baseline (648.138 us; speedup 1.0000x reference)
//
#include <hip/hip_runtime.h>
#include <math.h>

// Problem constants
#define BB 32
#define NN 8192
#define CC 64
#define SS 64    // NUM_NODE
#define KK 64    // NSAMPLE

// Workspace layout (in floats)
#define WS_FIDX   0         // int[2048]
#define WS_NLOC   270336    // float[2048*3]
#define WS_GIDX2  276480    // int[2048*64]
#define WS_PART   407552    // float[512*4160]
#define WS_TOT    2537472   // float[4160]
#define WS_SCALE  2541632   // float[64]
#define WS_SHIFT  2541696   // float[64]

// ---------------------------------------------------------------------------
// Phase 1 (fused, 512 threads): blocks 0..31 = FPS, 32..4127 = transpose,
// 4128..4639 = cov. fps is latency-bound; transpose+cov fill the other CUs.
// ---------------------------------------------------------------------------

__device__ __forceinline__ void fps_body(int b, const float* __restrict__ loc,
                                         int* __restrict__ fidx,
                                         float (*wrv)[8], int (*wri)[8],
                                         float (*wrx)[8], float (*wry)[8],
                                         float (*wrz)[8]) {
#pragma clang fp contract(off)
  __builtin_amdgcn_s_setprio(1);   // win issue arbitration vs bg waves
  int t = threadIdx.x;
  const float* lb = loc + (size_t)b * 3 * NN;
  float px[16], py[16], pz[16], dist[16];
#pragma unroll
  for (int k = 0; k < 16; k++) {
    int p = t + 512 * k;
    px[k] = lb[p];
    py[k] = lb[NN + p];
    pz[k] = lb[2 * NN + p];
    dist[k] = 1e10f;
  }
  int lane = t & 63, w = t >> 6;
  int far = 0;
  float cx = lb[0], cy = lb[NN], cz = lb[2 * NN];   // centroid 0 = point 0
  for (int it = 0; it < 64; it++) {
    if (t == 0) fidx[b * 64 + it] = far;
    float bv = -1.0f; int bi = 0;
    float bx = 0.f, by = 0.f, bz = 0.f;
#pragma unroll
    for (int k = 0; k < 16; k++) {
      float dx = px[k] - cx, dy = py[k] - cy, dz = pz[k] - cz;
      float d = (dx * dx + dy * dy) + dz * dz;
      float dm = dist[k];
      dm = d < dm ? d : dm;
      dist[k] = dm;
      if (dm > bv) { bv = dm; bi = t + 512 * k; bx = px[k]; by = py[k]; bz = pz[k]; }
    }
    float v = bv; int vi = bi;
    float vx = bx, vy = by, vz = bz;
#pragma unroll
    for (int off = 1; off < 64; off <<= 1) {
      float v2 = __shfl_xor(v, off, 64);
      int   i2 = __shfl_xor(vi, off, 64);
      float x2 = __shfl_xor(vx, off, 64);
      float y2 = __shfl_xor(vy, off, 64);
      float z2 = __shfl_xor(vz, off, 64);
      if (v2 > v || (v2 == v && i2 < vi)) { v = v2; vi = i2; vx = x2; vy = y2; vz = z2; }
    }
    int par = it & 1;
    if (lane == 0) {
      wrv[par][w] = v; wri[par][w] = vi;
      wrx[par][w] = vx; wry[par][w] = vy; wrz[par][w] = vz;
    }
    __syncthreads();
    float gv = wrv[par][0]; int gi = wri[par][0];
    float gx = wrx[par][0], gy = wry[par][0], gz = wrz[par][0];
#pragma unroll
    for (int w2 = 1; w2 < 8; w2++) {
      float v2 = wrv[par][w2]; int i2 = wri[par][w2];
      if (v2 > gv || (v2 == gv && i2 < gi)) {
        gv = v2; gi = i2;
        gx = wrx[par][w2]; gy = wry[par][w2]; gz = wrz[par][w2];
      }
    }
    far = gi;                    // identical on every thread
    cx = gx; cy = gy; cz = gz;   // next centroid from registers — no load
  }
}

__device__ __forceinline__ void transpose_body(int tb, const float* __restrict__ fea,
                                               float* __restrict__ feaT, float* tile) {
  int b = tb >> 7;            // 128 n-chunks per batch
  int n0 = (tb & 127) * 64;
  int t = threadIdx.x;
  const float* fb = fea + (size_t)b * (CC * NN);
#pragma unroll
  for (int m = 0; m < 8; m++) {
    int idx = m * 512 + t;
    int c = idx >> 6, nl = idx & 63;
    tile[c * 65 + nl] = fb[(size_t)c * NN + n0 + nl];
  }
  __syncthreads();
  float* ob = feaT + ((size_t)b * NN + n0) * 64;
#pragma unroll
  for (int m = 0; m < 8; m++) {
    int idx = m * 512 + t;
    int nl = idx >> 6, c = idx & 63;
    ob[idx] = tile[c * 65 + nl];
  }
}

__device__ __forceinline__ void cov_body(int cb, const float* __restrict__ fea,
                                         float* __restrict__ part,
                                         float* Sf, float* red) {
  int t = threadIdx.x, w = t >> 6, lane = t & 63;
  int i = lane >> 3, j = lane & 7;
  float acc[8][8];
  float rs[8];
#pragma unroll
  for (int r = 0; r < 8; r++) {
    rs[r] = 0.f;
#pragma unroll
    for (int r2 = 0; r2 < 8; r2++) acc[r][r2] = 0.f;
  }
  for (int q = 0; q < 4; q++) {
    int chunk = cb * 4 + q;
    int p0 = chunk * 128;
    int b = p0 >> 13, n0 = p0 & 8191;
    __syncthreads();
    const float* fb = fea + (size_t)b * (CC * NN) + n0;
    for (int m = 0; m < 16; m++) {
      int idx = m * 512 + t;
      int c = idx >> 7, pt = idx & 127;
      Sf[c * 133 + pt] = fb[(size_t)c * NN + pt];
    }
    __syncthreads();
    if (w < 4) {
      for (int pt = w * 32; pt < w * 32 + 32; pt++) {
        float a[8], bv[8];
#pragma unroll
        for (int r = 0; r < 8; r++) {
          a[r] = Sf[(8 * i + r) * 133 + pt];
          bv[r] = Sf[(8 * j + r) * 133 + pt];
        }
#pragma unroll
        for (int r = 0; r < 8; r++) {
          rs[r] += a[r];
#pragma unroll
          for (int r2 = 0; r2 < 8; r2++) acc[r][r2] = fmaf(a[r], bv[r2], acc[r][r2]);
        }
      }
    }
  }
  for (int ww = 0; ww < 4; ww++) {
    if (w == ww) {
#pragma unroll
      for (int r = 0; r < 8; r++) {
#pragma unroll
        for (int r2 = 0; r2 < 8; r2++) {
          int idx = (8 * i + r) * 64 + 8 * j + r2;
          if (ww == 0) red[idx] = acc[r][r2]; else red[idx] += acc[r][r2];
        }
        if (j == 0) {
          int ridx = 4096 + 8 * i + r;
          if (ww == 0) red[ridx] = rs[r]; else red[ridx] += rs[r];
        }
      }
    }
    __syncthreads();
  }
  float* pb = part + (size_t)cb * 4160;
  for (int idx = t; idx < 4160; idx += 512) pb[idx] = red[idx];
}

__global__ __launch_bounds__(512, 1) void phase1_kernel(const float* __restrict__ fea,
                                                        const float* __restrict__ loc,
                                                        float* __restrict__ feaT,
                                                        int* __restrict__ fidx,
                                                        float* __restrict__ part) {
  __shared__ __align__(16) char smem[50688];   // union: transpose 16640B, cov 50688B
  __shared__ float wrv[2][8], wrx[2][8], wry[2][8], wrz[2][8];
  __shared__ int wri[2][8];
  int blk = blockIdx.x;
  if (blk < 32) {
    fps_body(blk, loc, fidx, wrv, wri, wrx, wry, wrz);
  } else if (blk < 4128) {
    transpose_body(blk - 32, fea, feaT, (float*)smem);
  } else {
    cov_body(blk - 4128, fea, part, (float*)smem, (float*)(smem + 34048));
  }
}

// ---------------------------------------------------------------------------
// Mega kernel (restructured): blocks 0..2047 run the per-(b,s) chain
//   gather -> ball query (parallel masks) -> seman/node_loc -> kNN-64
// No keys[] array (selection uses register keys); ~20KB LDS -> 4 blocks/CU.
// Blocks 2048..2064 do covreduce.
// ---------------------------------------------------------------------------
__global__ __launch_bounds__(256) void mega_kernel(const float* __restrict__ loc,
                                                   const float* __restrict__ feaT,
                                                   const float* __restrict__ pw,
                                                   const int* __restrict__ fidx,
                                                   const float* __restrict__ part,
                                                   float* __restrict__ tot,
                                                   int* __restrict__ gidx2,
                                                   float* __restrict__ out_noff,
                                                   float* __restrict__ nloc) {
#pragma clang fp contract(off)
  int blk = blockIdx.x;
  if (blk >= 2048) {   // covreduce
    int e = (blk - 2048) * 256 + threadIdx.x;
    if (e < 4160) {
      float sum = 0.f;
      for (int b2 = 0; b2 < 512; b2++) sum += part[(size_t)b2 * 4160 + e];
      tot[e] = sum;
    }
    return;
  }
  int bs = blk, b = bs >> 6, s = bs & 63, t = threadIdx.x;
  int lane = t & 63, w = t >> 6;
  __shared__ unsigned long long masks[128];   // 1KB   ball-query ballots
  __shared__ unsigned hist[4096];             // 16KB  knn radix histogram
  __shared__ unsigned partl[256];             // 1KB
  __shared__ float sf[64];                    // fpoint_fea
  __shared__ float spw[192];                  // pred_w
  __shared__ float sl[3];                     // fpoint_loc
  __shared__ float sA[3];                     // node_loc
  __shared__ int gidxL[64];                   // ball-query result
  __shared__ unsigned wrk[4];                 // selection wave partials
  __shared__ int wrp[4];
  __shared__ unsigned selk;
  __shared__ int selp;
  __shared__ int sP, sC0, nOut;
  const float* lb = loc + (size_t)b * 3 * NN;

  if (t < 192) spw[t] = pw[t];
  if (w == 0) {
    int g = fidx[bs];
    sf[lane] = feaT[((size_t)b * NN + g) * 64 + lane];   // == fea[b][lane][g]
    if (lane < 3) sl[lane] = lb[(size_t)lane * NN + g];
  }
  __syncthreads();

  // ---- ball query: all 4 waves compute chunk ballot masks in parallel ----
  {
    float ax = sl[0], ay = sl[1], az = sl[2];
    float A = (ax * ax + ay * ay) + az * az;
    for (int cc = 0; cc < 32; cc++) {
      int ch = w * 32 + cc;
      int p = ch * 64 + lane;
      float bx = lb[p], by = lb[NN + p], bz = lb[2 * NN + p];
      float Bn = (bx * bx + by * by) + bz * bz;
      float dot = fmaf(az, bz, fmaf(ay, by, ax * bx));
      float sqr = (A + Bn) - 2.0f * dot;
      bool hit = !(sqr > 0.09f);
      unsigned long long m = __ballot(hit);
      if (lane == 0) masks[ch] = m;
    }
  }
  __syncthreads();

  // ---- ordered compaction (wave 0, ALU/LDS only; semantics identical) ----
  if (w == 0) {
    int count = 0, firsth = -1;
    for (int ch = 0; ch < 128 && count < 64; ch++) {
      unsigned long long m = masks[ch];
      if (m) {
        if (firsth < 0) firsth = ch * 64 + (int)__ffsll(m) - 1;
        bool hit = (m >> lane) & 1ull;
        int pos = count + (int)__popcll(m & ((1ull << lane) - 1ull));
        if (hit && pos < 64) gidxL[pos] = ch * 64 + lane;
        count += (int)__popcll(m);
      }
    }
    if (count < 64 && lane >= count) gidxL[lane] = firsth;
  }
  __syncthreads();

  // ---- seman / node_offset / node_loc (wave 0; identical math) ----
  if (w == 0) {
    int g = gidxL[lane];
    const float* fT = feaT + ((size_t)b * NN + g) * 64;
    float a0 = 0.f, a1 = 0.f, a2 = 0.f;
#pragma unroll
    for (int c4 = 0; c4 < 16; c4++) {
      float4 f = *(const float4*)(fT + 4 * c4);
      int c = 4 * c4;
      float g0 = f.x - sf[c + 0];
      a0 = fmaf(spw[c + 0], g0, a0); a1 = fmaf(spw[64 + c + 0], g0, a1); a2 = fmaf(spw[128 + c + 0], g0, a2);
      float g1 = f.y - sf[c + 1];
      a0 = fmaf(spw[c + 1], g1, a0); a1 = fmaf(spw[64 + c + 1], g1, a1); a2 = fmaf(spw[128 + c + 1], g1, a2);
      float g2 = f.z - sf[c + 2];
      a0 = fmaf(spw[c + 2], g2, a0); a1 = fmaf(spw[64 + c + 2], g2, a1); a2 = fmaf(spw[128 + c + 2], g2, a2);
      float g3 = f.w - sf[c + 3];
      a0 = fmaf(spw[c + 3], g3, a0); a1 = fmaf(spw[64 + c + 3], g3, a1); a2 = fmaf(spw[128 + c + 3], g3, a2);
    }
    float c0 = tanhf(a0) * (lb[g] - sl[0]);
    float c1 = tanhf(a1) * (lb[NN + g] - sl[1]);
    float c2 = tanhf(a2) * (lb[2 * NN + g] - sl[2]);
#pragma unroll
    for (int off = 32; off; off >>= 1) {
      c0 += __shfl_xor(c0, off, 64);
      c1 += __shfl_xor(c1, off, 64);
      c2 += __shfl_xor(c2, off, 64);
    }
    if (lane == 0) {
      float m0 = c0 * (1.0f / 64), m1 = c1 * (1.0f / 64), m2 = c2 * (1.0f / 64);
      out_noff[b * 192 + s] = m0;
      out_noff[b * 192 + 64 + s] = m1;
      out_noff[b * 192 + 128 + s] = m2;
      float nx = sl[0] + m0, ny = sl[1] + m1, nz = sl[2] + m2;
      nloc[bs * 3 + 0] = nx;
      nloc[bs * 3 + 1] = ny;
      nloc[bs * 3 + 2] = nz;
      sA[0] = nx; sA[1] = ny; sA[2] = nz;
    }
  }
  __syncthreads();

  // ---- kNN-64 radix select (keys live in registers only) ----
  float ax = sA[0], ay = sA[1], az = sA[2];
  float A = (ax * ax + ay * ay) + az * az;
  for (int m = 0; m < 16; m++) hist[m * 256 + t] = 0u;
  if (t == 0) nOut = 0;
  __syncthreads();
  unsigned mykey[32];
#pragma unroll
  for (int k = 0; k < 32; k++) {
    int p = t + 256 * k;
    float bx = lb[p], by = lb[NN + p], bz = lb[2 * NN + p];
    float Bn = (bx * bx + by * by) + bz * bz;
    float dot = fmaf(az, bz, fmaf(ay, by, ax * bx));
    float d = (A + Bn) - 2.0f * dot;
    unsigned kb = __float_as_uint(d);
    kb = (kb & 0x80000000u) ? ~kb : (kb | 0x80000000u);   // monotonic transform
    mykey[k] = kb;
    atomicAdd(&hist[kb >> 20], 1u);
  }
  __syncthreads();
  unsigned ps = 0;
#pragma unroll
  for (int m = 0; m < 16; m++) ps += hist[t * 16 + m];
  partl[t] = ps;
  __syncthreads();
  if (t == 0) {
    int cum = 0, seg = 0;
    for (int t2 = 0; t2 < 256; t2++) {
      if (cum + (int)partl[t2] >= 64) { seg = t2; break; }
      cum += (int)partl[t2];
    }
    int P = seg * 16;
    for (;; P++) {
      if (cum + (int)hist[P] >= 64) break;
      cum += (int)hist[P];
    }
    sP = P; sC0 = cum;
  }
  __syncthreads();
  int P = sP, C0 = sC0;
  // emit all points strictly below bin P (set semantics, order via atomics —
  // same as before; downstream max-pool is order-invariant)
#pragma unroll
  for (int k = 0; k < 32; k++) {
    if ((int)(mykey[k] >> 20) < P) {
      int pos = atomicAdd(&nOut, 1);
      gidx2[bs * 64 + pos] = t + 256 * k;
    }
  }
  // boundary bin: R rounds of block-wide register argmin in strictly
  // increasing (key,p) lexicographic order — identical picks to the old
  // candidate-list scan, no LDS keys needed.
  int R = 64 - C0;
  unsigned lastk = 0u; int lastp = -1;
  for (int r = 0; r < R; r++) {
    unsigned bk = 0xFFFFFFFFu; int bp = 0x7FFFFFFF;
#pragma unroll
    for (int k = 0; k < 32; k++) {
      unsigned kk = mykey[k];
      if ((int)(kk >> 20) == P) {
        int p = t + 256 * k;
        bool gt = (kk > lastk) || (kk == lastk && p > lastp);
        if (gt && (kk < bk || (kk == bk && p < bp))) { bk = kk; bp = p; }
      }
    }
#pragma unroll
    for (int off = 1; off < 64; off <<= 1) {
      unsigned k2 = __shfl_xor(bk, off, 64);
      int p2 = __shfl_xor(bp, off, 64);
      if (k2 < bk || (k2 == bk && p2 < bp)) { bk = k2; bp = p2; }
    }
    if (lane == 0) { wrk[w] = bk; wrp[w] = bp; }
    __syncthreads();
    if (t == 0) {
      unsigned fk = wrk[0]; int fp = wrp[0];
#pragma unroll
      for (int w2 = 1; w2 < 4; w2++) {
        unsigned k2 = wrk[w2]; int p2 = wrp[w2];
        if (k2 < fk || (k2 == fk && p2 < fp)) { fk = k2; fp = p2; }
      }
      gidx2[bs * 64 + C0 + r] = fp;
      selk = fk; selp = fp;
    }
    __syncthreads();
    lastk = selk; lastp = selp;
  }
}

// ---------------------------------------------------------------------------
// BN stats from channel moments (micro-kernel).
// ---------------------------------------------------------------------------
__global__ __launch_bounds__(64) void bnstats_kernel(const float* __restrict__ tot,
                                                     const float* __restrict__ rw,
                                                     const float* __restrict__ rb,
                                                     const float* __restrict__ gam,
                                                     const float* __restrict__ bet,
                                                     float* __restrict__ bnsc,
                                                     float* __restrict__ bnsh) {
  int o = threadIdx.x;
  const float invM = 1.0f / 262144.0f;
  float mu = 0.f;
  for (int c = 0; c < 64; c++) mu += rw[o * 64 + c] * (tot[4096 + c] * invM);
  float exx = 0.f;
  for (int c = 0; c < 64; c++) {
    const float* row = tot + c * 64;
    float p = 0.f;
    for (int c2 = 0; c2 < 64; c2++) p += rw[o * 64 + c2] * row[c2];
    exx += rw[o * 64 + c] * p;
  }
  exx *= invM;
  float var = exx - mu * mu;
  float mean = mu + rb[o];
  float sc = gam[o] / sqrtf(var + 1e-5f);
  bnsc[o] = sc;
  bnsh[o] = bet[o] - mean * sc;
}

// ---------------------------------------------------------------------------
// node_fea = max_k relu(BN(W . fea[gidx2])). Gather via feaT (coalesced).
// ---------------------------------------------------------------------------
__global__ __launch_bounds__(256) void nodefea_kernel(const float* __restrict__ feaT,
                                                      const float* __restrict__ rw,
                                                      const int* __restrict__ gidx2,
                                                      const float* __restrict__ bnsc,
                                                      const float* __restrict__ bnsh,
                                                      float* __restrict__ out_nf) {
  __shared__ __align__(16) float Lf[4096];  // [k][c]
  __shared__ float Lw[4096];                // [c][o] = rw[o][c]
  __shared__ int Lg[64];
  __shared__ float red[256];
  int bs = blockIdx.x, b = bs >> 6, s = bs & 63, t = threadIdx.x;
  if (t < 64) Lg[t] = gidx2[bs * 64 + t];
  __syncthreads();
#pragma unroll
  for (int m = 0; m < 4; m++) {
    int idx4 = m * 256 + t;               // 1024 float4s
    int k = idx4 >> 4, c4 = idx4 & 15;
    float4 f = *(const float4*)(feaT + ((size_t)b * NN + Lg[k]) * 64 + 4 * c4);
    *(float4*)&Lf[idx4 * 4] = f;
  }
  for (int m = 0; m < 16; m++) {
    int idx = m * 256 + t;
    Lw[idx] = rw[(idx & 63) * 64 + (idx >> 6)];
  }
  __syncthreads();
  int o = t & 63, wq = t >> 6;
  float wreg[64];
#pragma unroll
  for (int c = 0; c < 64; c++) wreg[c] = Lw[c * 64 + o];
  float sc = bnsc[o], sh = bnsh[o];
  float mx = -1e30f;
  for (int k = wq * 16; k < wq * 16 + 16; k++) {
    float raw = 0.f;
#pragma unroll
    for (int c4 = 0; c4 < 16; c4++) {
      float4 lf = *(const float4*)&Lf[k * 64 + c4 * 4];
      raw = fmaf(wreg[4 * c4 + 0], lf.x, raw);
      raw = fmaf(wreg[4 * c4 + 1], lf.y, raw);
      raw = fmaf(wreg[4 * c4 + 2], lf.z, raw);
      raw = fmaf(wreg[4 * c4 + 3], lf.w, raw);
    }
    float v = raw * sc + sh;
    v = v > 0.f ? v : 0.f;
    mx = v > mx ? v : mx;
  }
  red[wq * 64 + o] = mx;
  __syncthreads();
  if (t < 64) {
    float m0 = red[t], m1 = red[64 + t], m2 = red[128 + t], m3 = red[192 + t];
    float ma = m0 > m1 ? m0 : m1;
    float mb = m2 > m3 ? m2 : m3;
    float m = ma > mb ? ma : mb;
    out_nf[b * 4096 + t * 64 + s] = m;   // node_fea[b][o=t][s]
  }
}

// ---------------------------------------------------------------------------
// 3-NN inverse-distance interpolation + input_fea passthrough.
// node_fea staged in LDS (removes 192 scattered global reads per thread).
// ---------------------------------------------------------------------------
__global__ __launch_bounds__(256) void interp_kernel(const float* __restrict__ fea,
                                                     const float* __restrict__ loc,
                                                     const float* __restrict__ nloc,
                                                     const float* __restrict__ nf,
                                                     float* __restrict__ out) {
#pragma clang fp contract(off)
  int b = blockIdx.y;
  int t = threadIdx.x;
  int n = blockIdx.x * 256 + t;
  __shared__ float snl[192];
  __shared__ float sB[64];
  __shared__ float snf[4096];   // nf[b] staged (16KB)
  if (t < 192) snl[t] = nloc[b * 192 + t];
  {
    const float* nfb = nf + b * 4096;
#pragma unroll
    for (int m = 0; m < 16; m++) snf[m * 256 + t] = nfb[m * 256 + t];
  }
  __syncthreads();
  if (t < 64) {
    float x = snl[t * 3], y = snl[t * 3 + 1], z = snl[t * 3 + 2];
    sB[t] = (x * x + y * y) + z * z;
  }
  __syncthreads();
  const float* lb = loc + (size_t)b * 3 * NN;
  float px = lb[n], py = lb[NN + n], pz = lb[2 * NN + n];
  float A = (px * px + py * py) + pz * pz;
  float d0 = 1e30f, d1 = 1e30f, d2 = 1e30f;
  int i0 = 0, i1 = 0, i2 = 0;
  for (int s = 0; s < 64; s++) {
    float dot = fmaf(pz, snl[s * 3 + 2], fmaf(py, snl[s * 3 + 1], px * snl[s * 3]));
    float d = (A + sB[s]) - 2.0f * dot;
    if (d < d0) { d2 = d1; i2 = i1; d1 = d0; i1 = i0; d0 = d; i0 = s; }
    else if (d < d1) { d2 = d1; i2 = i1; d1 = d; i1 = s; }
    else if (d < d2) { d2 = d; i2 = s; }
  }
  d0 = d0 > 1e-10f ? d0 : 1e-10f;
  d1 = d1 > 1e-10f ? d1 : 1e-10f;
  d2 = d2 > 1e-10f ? d2 : 1e-10f;
  float r0 = 1.0f / d0, r1 = 1.0f / d1, r2 = 1.0f / d2;
  float rsum = (r0 + r1) + r2;
  float w0 = r0 / rsum, w1 = r1 / rsum, w2 = r2 / rsum;
  const float* fb = fea + (size_t)b * (CC * NN);
  float* ob = out + (size_t)b * (128 * NN);
  for (int o = 0; o < 64; o++) {
    ob[(size_t)o * NN + n] = fb[(size_t)o * NN + n];
    float ip = (snf[o * 64 + i0] * w0 + snf[o * 64 + i1] * w1) + snf[o * 64 + i2] * w2;
    ob[(size_t)(64 + o) * NN + n] = ip;
  }
}

// ---------------------------------------------------------------------------
extern "C" void kernel_launch(void* const* d_in, const int* in_sizes, int n_in,
                              void* d_out, int out_size, void* d_ws, size_t ws_size,
                              hipStream_t stream) {
  (void)in_sizes; (void)n_in; (void)out_size; (void)ws_size;
  const float* fea = (const float*)d_in[0];
  const float* loc = (const float*)d_in[1];
  const float* pw  = (const float*)d_in[2];
  const float* rw  = (const float*)d_in[3];
  const float* rb  = (const float*)d_in[4];
  const float* gam = (const float*)d_in[5];
  const float* bet = (const float*)d_in[6];
  float* out = (float*)d_out;
  float* ws = (float*)d_ws;

  int*   fidx  = (int*)(ws + WS_FIDX);
  float* nlocp = ws + WS_NLOC;
  int*   gidx2 = (int*)(ws + WS_GIDX2);
  float* part  = ws + WS_PART;
  float* tot   = ws + WS_TOT;
  float* bnsc  = ws + WS_SCALE;
  float* bnsh  = ws + WS_SHIFT;

  float* feaT     = out;             // 64 MB scratch; overwritten by interp last
  float* out_nf   = out + 33554432;  // node_fea   (B,64,64,1)
  float* out_noff = out + 33685504;  // node_offset(B,3,64)

  // Phase 1: fps (32 blocks) + transpose (4096) + cov (512) run concurrently.
  phase1_kernel<<<dim3(4640), dim3(512), 0, stream>>>(fea, loc, feaT, fidx, part);
  // Mega: per-(b,s) gather+ball+seman+knn (2048 blocks) + covreduce (17).
  mega_kernel<<<dim3(2065), dim3(256), 0, stream>>>(loc, feaT, pw, fidx, part, tot,
                                                    gidx2, out_noff, nlocp);
  bnstats_kernel<<<dim3(1), dim3(64), 0, stream>>>(tot, rw, rb, gam, bet, bnsc, bnsh);
  nodefea_kernel<<<dim3(2048), dim3(256), 0, stream>>>(feaT, rw, gidx2, bnsc, bnsh, out_nf);
  interp_kernel<<<dim3(32, 32), dim3(256), 0, stream>>>(fea, loc, nlocp, out_nf, out);
}

// Round 5
// 592.586 us; speedup vs baseline: 1.0937x; 1.0937x over previous
//
#include <hip/hip_runtime.h>
#include <math.h>

// Problem constants
#define BB 32
#define NN 8192
#define CC 64
#define SS 64    // NUM_NODE
#define KK 64    // NSAMPLE

// Workspace layout (in floats)
#define WS_FIDX   0         // int[2048]
#define WS_FLOC   2048      // float[2048*3]
#define WS_FFEA   8192      // float[2048*64]
#define WS_GIDX   139264    // int[2048*64]
#define WS_NLOC   270336    // float[2048*3]
#define WS_GIDX2  276480    // int[2048*64]
#define WS_PART   407552    // float[512*4160]
#define WS_TOT    2537472   // float[4160]
#define WS_SCALE  2541632   // float[64]
#define WS_SHIFT  2541696   // float[64]

// ---------------------------------------------------------------------------
// Phase 1 (fused, 512 threads): blocks 0..31 = FPS, 32..4127 = transpose,
// 4128..4639 = cov. fps is latency-bound; transpose+cov fill the other CUs.
// ---------------------------------------------------------------------------

// FPS: 512 threads, 16 pts/thread in registers; winning point's coordinates
// carried through the reduction so no dependent load per iteration.
// Selection semantics identical to reference: global argmax, min-index ties.
__device__ __forceinline__ void fps_body(int b, const float* __restrict__ loc,
                                         int* __restrict__ fidx,
                                         float (*wrv)[8], int (*wri)[8],
                                         float (*wrx)[8], float (*wry)[8],
                                         float (*wrz)[8]) {
#pragma clang fp contract(off)
  __builtin_amdgcn_s_setprio(1);   // win issue arbitration vs bg waves
  int t = threadIdx.x;
  const float* lb = loc + (size_t)b * 3 * NN;
  float px[16], py[16], pz[16], dist[16];
#pragma unroll
  for (int k = 0; k < 16; k++) {
    int p = t + 512 * k;
    px[k] = lb[p];
    py[k] = lb[NN + p];
    pz[k] = lb[2 * NN + p];
    dist[k] = 1e10f;
  }
  int lane = t & 63, w = t >> 6;
  int far = 0;
  float cx = lb[0], cy = lb[NN], cz = lb[2 * NN];   // centroid 0 = point 0
  for (int it = 0; it < 64; it++) {
    if (t == 0) fidx[b * 64 + it] = far;
    float bv = -1.0f; int bi = 0;
    float bx = 0.f, by = 0.f, bz = 0.f;
#pragma unroll
    for (int k = 0; k < 16; k++) {
      float dx = px[k] - cx, dy = py[k] - cy, dz = pz[k] - cz;
      float d = (dx * dx + dy * dy) + dz * dz;
      float dm = dist[k];
      dm = d < dm ? d : dm;
      dist[k] = dm;
      if (dm > bv) { bv = dm; bi = t + 512 * k; bx = px[k]; by = py[k]; bz = pz[k]; }
    }
    float v = bv; int vi = bi;
    float vx = bx, vy = by, vz = bz;
#pragma unroll
    for (int off = 1; off < 64; off <<= 1) {
      float v2 = __shfl_xor(v, off, 64);
      int   i2 = __shfl_xor(vi, off, 64);
      float x2 = __shfl_xor(vx, off, 64);
      float y2 = __shfl_xor(vy, off, 64);
      float z2 = __shfl_xor(vz, off, 64);
      if (v2 > v || (v2 == v && i2 < vi)) { v = v2; vi = i2; vx = x2; vy = y2; vz = z2; }
    }
    int par = it & 1;
    if (lane == 0) {
      wrv[par][w] = v; wri[par][w] = vi;
      wrx[par][w] = vx; wry[par][w] = vy; wrz[par][w] = vz;
    }
    __syncthreads();
    float gv = wrv[par][0]; int gi = wri[par][0];
    float gx = wrx[par][0], gy = wry[par][0], gz = wrz[par][0];
#pragma unroll
    for (int w2 = 1; w2 < 8; w2++) {
      float v2 = wrv[par][w2]; int i2 = wri[par][w2];
      if (v2 > gv || (v2 == gv && i2 < gi)) {
        gv = v2; gi = i2;
        gx = wrx[par][w2]; gy = wry[par][w2]; gz = wrz[par][w2];
      }
    }
    far = gi;                    // identical on every thread
    cx = gx; cy = gy; cz = gz;   // next centroid from registers — no load
  }
}

// Transpose body (512 thr): fea[b][c][n] -> feaT[b][n][c]. For b>=16 also
// writes the fea passthrough into out[b][c][n] (that region starts at float
// 16*128*8192 = 16777216, exactly past feaT's [0,16777216) — no overlap),
// removing those reads+writes from interp's critical-path tail.
__device__ __forceinline__ void transpose_body(int tb, const float* __restrict__ fea,
                                               float* __restrict__ feaT,
                                               float* __restrict__ out, float* tile) {
  int b = tb >> 7;            // 128 n-chunks per batch
  int n0 = (tb & 127) * 64;
  int t = threadIdx.x;
  const float* fb = fea + (size_t)b * (CC * NN);
  float* pb = out + (size_t)b * (128 * NN);
  bool pass = (b >= 16);
#pragma unroll
  for (int m = 0; m < 8; m++) {
    int idx = m * 512 + t;
    int c = idx >> 6, nl = idx & 63;
    float v = fb[(size_t)c * NN + n0 + nl];
    tile[c * 65 + nl] = v;
    if (pass) pb[(size_t)c * NN + n0 + nl] = v;
  }
  __syncthreads();
  float* ob = feaT + ((size_t)b * NN + n0) * 64;
#pragma unroll
  for (int m = 0; m < 8; m++) {
    int idx = m * 512 + t;
    int nl = idx >> 6, c = idx & 63;
    ob[idx] = tile[c * 65 + nl];
  }
}

// Cov body (512 thr): compute waves 0-3 keep the EXACT summation order of the
// original 256-thread kernel (bit-identical BN stats); waves 4-7 only help
// with the pure LDS staging loads.
__device__ __forceinline__ void cov_body(int cb, const float* __restrict__ fea,
                                         float* __restrict__ part,
                                         float* Sf, float* red) {
  int t = threadIdx.x, w = t >> 6, lane = t & 63;
  int i = lane >> 3, j = lane & 7;
  float acc[8][8];
  float rs[8];
#pragma unroll
  for (int r = 0; r < 8; r++) {
    rs[r] = 0.f;
#pragma unroll
    for (int r2 = 0; r2 < 8; r2++) acc[r][r2] = 0.f;
  }
  for (int q = 0; q < 4; q++) {
    int chunk = cb * 4 + q;
    int p0 = chunk * 128;
    int b = p0 >> 13, n0 = p0 & 8191;
    __syncthreads();
    const float* fb = fea + (size_t)b * (CC * NN) + n0;
    for (int m = 0; m < 16; m++) {
      int idx = m * 512 + t;
      int c = idx >> 7, pt = idx & 127;
      Sf[c * 133 + pt] = fb[(size_t)c * NN + pt];
    }
    __syncthreads();
    if (w < 4) {
      for (int pt = w * 32; pt < w * 32 + 32; pt++) {
        float a[8], bv[8];
#pragma unroll
        for (int r = 0; r < 8; r++) {
          a[r] = Sf[(8 * i + r) * 133 + pt];
          bv[r] = Sf[(8 * j + r) * 133 + pt];
        }
#pragma unroll
        for (int r = 0; r < 8; r++) {
          rs[r] += a[r];
#pragma unroll
          for (int r2 = 0; r2 < 8; r2++) acc[r][r2] = fmaf(a[r], bv[r2], acc[r][r2]);
        }
      }
    }
  }
  for (int ww = 0; ww < 4; ww++) {
    if (w == ww) {
#pragma unroll
      for (int r = 0; r < 8; r++) {
#pragma unroll
        for (int r2 = 0; r2 < 8; r2++) {
          int idx = (8 * i + r) * 64 + 8 * j + r2;
          if (ww == 0) red[idx] = acc[r][r2]; else red[idx] += acc[r][r2];
        }
        if (j == 0) {
          int ridx = 4096 + 8 * i + r;
          if (ww == 0) red[ridx] = rs[r]; else red[ridx] += rs[r];
        }
      }
    }
    __syncthreads();
  }
  float* pb = part + (size_t)cb * 4160;
  for (int idx = t; idx < 4160; idx += 512) pb[idx] = red[idx];
}

__global__ __launch_bounds__(512, 1) void phase1_kernel(const float* __restrict__ fea,
                                                        const float* __restrict__ loc,
                                                        float* __restrict__ feaT,
                                                        float* __restrict__ out,
                                                        int* __restrict__ fidx,
                                                        float* __restrict__ part) {
  __shared__ __align__(16) char smem[50688];   // union: transpose 16640B, cov 50688B
  __shared__ float wrv[2][8], wrx[2][8], wry[2][8], wrz[2][8];
  __shared__ int wri[2][8];
  int blk = blockIdx.x;
  if (blk < 32) {
    fps_body(blk, loc, fidx, wrv, wri, wrx, wry, wrz);
  } else if (blk < 4128) {
    transpose_body(blk - 32, fea, feaT, out, (float*)smem);
  } else {
    cov_body(blk - 4128, fea, part, (float*)smem, (float*)(smem + 34048));
  }
}

// ---------------------------------------------------------------------------
// Phase 2 (fused): blocks 0..16 = covreduce, 17..528 = gather (4 bs per block).
// ---------------------------------------------------------------------------
__global__ __launch_bounds__(256) void phase2_kernel(const float* __restrict__ part,
                                                     float* __restrict__ tot,
                                                     const float* __restrict__ loc,
                                                     const float* __restrict__ fea,
                                                     const int* __restrict__ fidx,
                                                     float* __restrict__ floc,
                                                     float* __restrict__ ffea) {
  int blk = blockIdx.x, t = threadIdx.x;
  if (blk < 17) {
    int e = blk * 256 + t;
    if (e >= 4160) return;
    float s = 0.f;
    for (int b2 = 0; b2 < 512; b2++) s += part[(size_t)b2 * 4160 + e];
    tot[e] = s;
  } else {
    int bs = (blk - 17) * 4 + (t >> 6);
    int c = t & 63;
    int b = bs >> 6;
    int g = fidx[bs];
    ffea[bs * 64 + c] = fea[(size_t)b * (CC * NN) + (size_t)c * NN + g];
    if (c < 3) floc[bs * 3 + c] = loc[(size_t)b * (3 * NN) + (size_t)c * NN + g];
  }
}

// ---------------------------------------------------------------------------
// Phase 3 (fused): blocks 0..511 = ball query (radius, EARLY EXIT),
// block 512 = bnstats.
// ---------------------------------------------------------------------------
__global__ __launch_bounds__(256) void phase3_kernel(const float* __restrict__ loc,
                                                     const float* __restrict__ floc,
                                                     int* __restrict__ gidx,
                                                     const float* __restrict__ tot,
                                                     const float* __restrict__ rw,
                                                     const float* __restrict__ rb,
                                                     const float* __restrict__ gam,
                                                     const float* __restrict__ bet,
                                                     float* __restrict__ bnsc,
                                                     float* __restrict__ bnsh) {
#pragma clang fp contract(off)
  int blk = blockIdx.x;
  if (blk < 512) {
    int w = threadIdx.x >> 6, lane = threadIdx.x & 63;
    int bs = blk * 4 + w, b = bs >> 6;
    const float* lb = loc + (size_t)b * 3 * NN;
    float ax = floc[bs * 3], ay = floc[bs * 3 + 1], az = floc[bs * 3 + 2];
    float A = (ax * ax + ay * ay) + az * az;
    int count = 0, firsth = -1;
    for (int ch = 0; ch < 128 && count < 64; ch++) {
      int p = ch * 64 + lane;
      float bx = lb[p], by = lb[NN + p], bz = lb[2 * NN + p];
      float Bn = (bx * bx + by * by) + bz * bz;
      float dot = fmaf(az, bz, fmaf(ay, by, ax * bx));
      float sqr = (A + Bn) - 2.0f * dot;
      bool hit = !(sqr > 0.09f);
      unsigned long long m = __ballot(hit);
      if (m) {
        if (firsth < 0) firsth = ch * 64 + (int)__ffsll(m) - 1;
        int pos = count + (int)__popcll(m & ((1ull << lane) - 1ull));
        if (hit && pos < 64) gidx[bs * 64 + pos] = p;
        count += (int)__popcll(m);
      }
    }
    if (count < 64 && lane >= count) gidx[bs * 64 + lane] = firsth;
  } else {
    int o = threadIdx.x;
    if (o >= 64) return;
    const float invM = 1.0f / 262144.0f;
    float mu = 0.f;
    for (int c = 0; c < 64; c++) mu += rw[o * 64 + c] * (tot[4096 + c] * invM);
    float exx = 0.f;
    for (int c = 0; c < 64; c++) {
      const float* row = tot + c * 64;
      float p = 0.f;
      for (int c2 = 0; c2 < 64; c2++) p += rw[o * 64 + c2] * row[c2];
      exx += rw[o * 64 + c] * p;
    }
    exx *= invM;
    float var = exx - mu * mu;
    float mean = mu + rb[o];
    float sc = gam[o] / sqrtf(var + 1e-5f);
    bnsc[o] = sc;
    bnsh[o] = bet[o] - mean * sc;
  }
}

// ---------------------------------------------------------------------------
// seman/node_offset/node_loc. One wave per (b,s), lane = k.
// ---------------------------------------------------------------------------
__global__ __launch_bounds__(64) void seman_kernel(const float* __restrict__ feaT,
                                                   const float* __restrict__ loc,
                                                   const float* __restrict__ pw,
                                                   const int* __restrict__ gidx,
                                                   const float* __restrict__ ffea,
                                                   const float* __restrict__ floc,
                                                   float* __restrict__ out_noff,
                                                   float* __restrict__ nloc) {
  int bs = blockIdx.x, b = bs >> 6, s = bs & 63, k = threadIdx.x;
  __shared__ float sf[64];
  __shared__ float spw[192];
  __shared__ float sl[3];
  sf[k] = ffea[bs * 64 + k];
  spw[k] = pw[k]; spw[64 + k] = pw[64 + k]; spw[128 + k] = pw[128 + k];
  if (k < 3) sl[k] = floc[bs * 3 + k];
  __syncthreads();
  int g = gidx[bs * 64 + k];
  const float* fT = feaT + ((size_t)b * NN + g) * 64;
  float a0 = 0.f, a1 = 0.f, a2 = 0.f;
#pragma unroll
  for (int c4 = 0; c4 < 16; c4++) {
    float4 f = *(const float4*)(fT + 4 * c4);
    int c = 4 * c4;
    float g0 = f.x - sf[c + 0];
    a0 = fmaf(spw[c + 0], g0, a0); a1 = fmaf(spw[64 + c + 0], g0, a1); a2 = fmaf(spw[128 + c + 0], g0, a2);
    float g1 = f.y - sf[c + 1];
    a0 = fmaf(spw[c + 1], g1, a0); a1 = fmaf(spw[64 + c + 1], g1, a1); a2 = fmaf(spw[128 + c + 1], g1, a2);
    float g2 = f.z - sf[c + 2];
    a0 = fmaf(spw[c + 2], g2, a0); a1 = fmaf(spw[64 + c + 2], g2, a1); a2 = fmaf(spw[128 + c + 2], g2, a2);
    float g3 = f.w - sf[c + 3];
    a0 = fmaf(spw[c + 3], g3, a0); a1 = fmaf(spw[64 + c + 3], g3, a1); a2 = fmaf(spw[128 + c + 3], g3, a2);
  }
  const float* lb = loc + (size_t)b * 3 * NN;
  float c0 = tanhf(a0) * (lb[g] - sl[0]);
  float c1 = tanhf(a1) * (lb[NN + g] - sl[1]);
  float c2 = tanhf(a2) * (lb[2 * NN + g] - sl[2]);
#pragma unroll
  for (int off = 32; off; off >>= 1) {
    c0 += __shfl_xor(c0, off, 64);
    c1 += __shfl_xor(c1, off, 64);
    c2 += __shfl_xor(c2, off, 64);
  }
  if (k == 0) {
    float m0 = c0 * (1.0f / 64), m1 = c1 * (1.0f / 64), m2 = c2 * (1.0f / 64);
    out_noff[b * 192 + s] = m0;
    out_noff[b * 192 + 64 + s] = m1;
    out_noff[b * 192 + 128 + s] = m2;
    nloc[bs * 3 + 0] = sl[0] + m0;
    nloc[bs * 3 + 1] = sl[1] + m1;
    nloc[bs * 3 + 2] = sl[2] + m2;
  }
}

// ---------------------------------------------------------------------------
// kNN-64 radix select, keys in registers only (~17.5KB LDS).
// Identical picks to the candidate-list version: bins < P via atomic append
// (set semantics; downstream max-pool order-invariant), boundary bin in
// strictly increasing (key, p) lexicographic order.
// ---------------------------------------------------------------------------
__global__ __launch_bounds__(256) void knn_kernel(const float* __restrict__ loc,
                                                  const float* __restrict__ nloc,
                                                  int* __restrict__ gidx2) {
#pragma clang fp contract(off)
  int bs = blockIdx.x, b = bs >> 6, t = threadIdx.x;
  int lane = t & 63, w = t >> 6;
  const float* lb = loc + (size_t)b * 3 * NN;
  float ax = nloc[bs * 3], ay = nloc[bs * 3 + 1], az = nloc[bs * 3 + 2];
  float A = (ax * ax + ay * ay) + az * az;
  __shared__ unsigned hist[4096];
  __shared__ unsigned partl[256];
  __shared__ unsigned wrk[4];
  __shared__ int wrp[4];
  __shared__ unsigned selk;
  __shared__ int selp;
  __shared__ int sP, sC0, nOut;
  for (int m = 0; m < 16; m++) hist[m * 256 + t] = 0u;
  if (t == 0) nOut = 0;
  __syncthreads();
  unsigned mykey[32];
#pragma unroll
  for (int k = 0; k < 32; k++) {
    int p = t + 256 * k;
    float bx = lb[p], by = lb[NN + p], bz = lb[2 * NN + p];
    float Bn = (bx * bx + by * by) + bz * bz;
    float dot = fmaf(az, bz, fmaf(ay, by, ax * bx));
    float d = (A + Bn) - 2.0f * dot;
    unsigned kb = __float_as_uint(d);
    kb = (kb & 0x80000000u) ? ~kb : (kb | 0x80000000u);   // monotonic transform
    mykey[k] = kb;
    atomicAdd(&hist[kb >> 20], 1u);
  }
  __syncthreads();
  unsigned ps = 0;
#pragma unroll
  for (int m = 0; m < 16; m++) ps += hist[t * 16 + m];
  partl[t] = ps;
  __syncthreads();
  if (t == 0) {
    int cum = 0, seg = 0;
    for (int t2 = 0; t2 < 256; t2++) {
      if (cum + (int)partl[t2] >= 64) { seg = t2; break; }
      cum += (int)partl[t2];
    }
    int P = seg * 16;
    for (;; P++) {
      if (cum + (int)hist[P] >= 64) break;
      cum += (int)hist[P];
    }
    sP = P; sC0 = cum;
  }
  __syncthreads();
  int P = sP, C0 = sC0;
#pragma unroll
  for (int k = 0; k < 32; k++) {
    if ((int)(mykey[k] >> 20) < P) {
      int pos = atomicAdd(&nOut, 1);
      gidx2[bs * 64 + pos] = t + 256 * k;
    }
  }
  int R = 64 - C0;
  unsigned lastk = 0u; int lastp = -1;
  for (int r = 0; r < R; r++) {
    unsigned bk = 0xFFFFFFFFu; int bp = 0x7FFFFFFF;
#pragma unroll
    for (int k = 0; k < 32; k++) {
      unsigned kk = mykey[k];
      if ((int)(kk >> 20) == P) {
        int p = t + 256 * k;
        bool gt = (kk > lastk) || (kk == lastk && p > lastp);
        if (gt && (kk < bk || (kk == bk && p < bp))) { bk = kk; bp = p; }
      }
    }
#pragma unroll
    for (int off = 1; off < 64; off <<= 1) {
      unsigned k2 = __shfl_xor(bk, off, 64);
      int p2 = __shfl_xor(bp, off, 64);
      if (k2 < bk || (k2 == bk && p2 < bp)) { bk = k2; bp = p2; }
    }
    if (lane == 0) { wrk[w] = bk; wrp[w] = bp; }
    __syncthreads();
    if (t == 0) {
      unsigned fk = wrk[0]; int fp = wrp[0];
#pragma unroll
      for (int w2 = 1; w2 < 4; w2++) {
        unsigned k2 = wrk[w2]; int p2 = wrp[w2];
        if (k2 < fk || (k2 == fk && p2 < fp)) { fk = k2; fp = p2; }
      }
      gidx2[bs * 64 + C0 + r] = fp;
      selk = fk; selp = fp;
    }
    __syncthreads();
    lastk = selk; lastp = selp;
  }
}

// ---------------------------------------------------------------------------
// node_fea = max_k relu(BN(W . fea[gidx2])). Gather via feaT (coalesced).
// ---------------------------------------------------------------------------
__global__ __launch_bounds__(256) void nodefea_kernel(const float* __restrict__ feaT,
                                                      const float* __restrict__ rw,
                                                      const int* __restrict__ gidx2,
                                                      const float* __restrict__ bnsc,
                                                      const float* __restrict__ bnsh,
                                                      float* __restrict__ out_nf) {
  __shared__ __align__(16) float Lf[4096];  // [k][c]
  __shared__ float Lw[4096];                // [c][o] = rw[o][c]
  __shared__ int Lg[64];
  __shared__ float red[256];
  int bs = blockIdx.x, b = bs >> 6, s = bs & 63, t = threadIdx.x;
  if (t < 64) Lg[t] = gidx2[bs * 64 + t];
  __syncthreads();
#pragma unroll
  for (int m = 0; m < 4; m++) {
    int idx4 = m * 256 + t;               // 1024 float4s
    int k = idx4 >> 4, c4 = idx4 & 15;
    float4 f = *(const float4*)(feaT + ((size_t)b * NN + Lg[k]) * 64 + 4 * c4);
    *(float4*)&Lf[idx4 * 4] = f;
  }
  for (int m = 0; m < 16; m++) {
    int idx = m * 256 + t;
    Lw[idx] = rw[(idx & 63) * 64 + (idx >> 6)];
  }
  __syncthreads();
  int o = t & 63, wq = t >> 6;
  float wreg[64];
#pragma unroll
  for (int c = 0; c < 64; c++) wreg[c] = Lw[c * 64 + o];
  float sc = bnsc[o], sh = bnsh[o];
  float mx = -1e30f;
  for (int k = wq * 16; k < wq * 16 + 16; k++) {
    float raw = 0.f;
#pragma unroll
    for (int c4 = 0; c4 < 16; c4++) {
      float4 lf = *(const float4*)&Lf[k * 64 + c4 * 4];
      raw = fmaf(wreg[4 * c4 + 0], lf.x, raw);
      raw = fmaf(wreg[4 * c4 + 1], lf.y, raw);
      raw = fmaf(wreg[4 * c4 + 2], lf.z, raw);
      raw = fmaf(wreg[4 * c4 + 3], lf.w, raw);
    }
    float v = raw * sc + sh;
    v = v > 0.f ? v : 0.f;
    mx = v > mx ? v : mx;
  }
  red[wq * 64 + o] = mx;
  __syncthreads();
  if (t < 64) {
    float m0 = red[t], m1 = red[64 + t], m2 = red[128 + t], m3 = red[192 + t];
    float ma = m0 > m1 ? m0 : m1;
    float mb = m2 > m3 ? m2 : m3;
    float m = ma > mb ? ma : mb;
    out_nf[b * 4096 + t * 64 + s] = m;   // node_fea[b][o=t][s]
  }
}

// ---------------------------------------------------------------------------
// 3-NN inverse-distance interpolation. node_fea staged in LDS. Passthrough
// only for b<16 (b>=16 was written by transpose in phase1).
// ---------------------------------------------------------------------------
__global__ __launch_bounds__(256) void interp_kernel(const float* __restrict__ fea,
                                                     const float* __restrict__ loc,
                                                     const float* __restrict__ nloc,
                                                     const float* __restrict__ nf,
                                                     float* __restrict__ out) {
#pragma clang fp contract(off)
  int b = blockIdx.y;
  int t = threadIdx.x;
  int n = blockIdx.x * 256 + t;
  __shared__ float snl[192];
  __shared__ float sB[64];
  __shared__ float snf[4096];   // nf[b] staged (16KB)
  if (t < 192) snl[t] = nloc[b * 192 + t];
  {
    const float* nfb = nf + b * 4096;
#pragma unroll
    for (int m = 0; m < 16; m++) snf[m * 256 + t] = nfb[m * 256 + t];
  }
  __syncthreads();
  if (t < 64) {
    float x = snl[t * 3], y = snl[t * 3 + 1], z = snl[t * 3 + 2];
    sB[t] = (x * x + y * y) + z * z;
  }
  __syncthreads();
  const float* lb = loc + (size_t)b * 3 * NN;
  float px = lb[n], py = lb[NN + n], pz = lb[2 * NN + n];
  float A = (px * px + py * py) + pz * pz;
  float d0 = 1e30f, d1 = 1e30f, d2 = 1e30f;
  int i0 = 0, i1 = 0, i2 = 0;
  for (int s = 0; s < 64; s++) {
    float dot = fmaf(pz, snl[s * 3 + 2], fmaf(py, snl[s * 3 + 1], px * snl[s * 3]));
    float d = (A + sB[s]) - 2.0f * dot;
    if (d < d0) { d2 = d1; i2 = i1; d1 = d0; i1 = i0; d0 = d; i0 = s; }
    else if (d < d1) { d2 = d1; i2 = i1; d1 = d; i1 = s; }
    else if (d < d2) { d2 = d; i2 = s; }
  }
  d0 = d0 > 1e-10f ? d0 : 1e-10f;
  d1 = d1 > 1e-10f ? d1 : 1e-10f;
  d2 = d2 > 1e-10f ? d2 : 1e-10f;
  float r0 = 1.0f / d0, r1 = 1.0f / d1, r2 = 1.0f / d2;
  float rsum = (r0 + r1) + r2;
  float w0 = r0 / rsum, w1 = r1 / rsum, w2 = r2 / rsum;
  const float* fb = fea + (size_t)b * (CC * NN);
  float* ob = out + (size_t)b * (128 * NN);
  bool pass = (b < 16);
  for (int o = 0; o < 64; o++) {
    if (pass) ob[(size_t)o * NN + n] = fb[(size_t)o * NN + n];
    float ip = (snf[o * 64 + i0] * w0 + snf[o * 64 + i1] * w1) + snf[o * 64 + i2] * w2;
    ob[(size_t)(64 + o) * NN + n] = ip;
  }
}

// ---------------------------------------------------------------------------
extern "C" void kernel_launch(void* const* d_in, const int* in_sizes, int n_in,
                              void* d_out, int out_size, void* d_ws, size_t ws_size,
                              hipStream_t stream) {
  (void)in_sizes; (void)n_in; (void)out_size; (void)ws_size;
  const float* fea = (const float*)d_in[0];
  const float* loc = (const float*)d_in[1];
  const float* pw  = (const float*)d_in[2];
  const float* rw  = (const float*)d_in[3];
  const float* rb  = (const float*)d_in[4];
  const float* gam = (const float*)d_in[5];
  const float* bet = (const float*)d_in[6];
  float* out = (float*)d_out;
  float* ws = (float*)d_ws;

  int*   fidx  = (int*)(ws + WS_FIDX);
  float* floc  = ws + WS_FLOC;
  float* ffea  = ws + WS_FFEA;
  int*   gidx  = (int*)(ws + WS_GIDX);
  float* nlocp = ws + WS_NLOC;
  int*   gidx2 = (int*)(ws + WS_GIDX2);
  float* part  = ws + WS_PART;
  float* tot   = ws + WS_TOT;
  float* bnsc  = ws + WS_SCALE;
  float* bnsh  = ws + WS_SHIFT;

  float* feaT     = out;             // 64 MB scratch (batches 0-15 region)
  float* out_nf   = out + 33554432;  // node_fea   (B,64,64,1)
  float* out_noff = out + 33685504;  // node_offset(B,3,64)

  // Phase 1: fps (32) + transpose/passthrough (4096) + cov (512) concurrent.
  phase1_kernel<<<dim3(4640), dim3(512), 0, stream>>>(fea, loc, feaT, out, fidx, part);
  // Phase 2: covreduce (17) + fpoint gather (512).
  phase2_kernel<<<dim3(529), dim3(256), 0, stream>>>(part, tot, loc, fea, fidx, floc, ffea);
  // Phase 3: ball query w/ early exit (512) + bnstats (1).
  phase3_kernel<<<dim3(513), dim3(256), 0, stream>>>(loc, floc, gidx, tot, rw, rb, gam, bet, bnsc, bnsh);
  seman_kernel<<<dim3(2048), dim3(64), 0, stream>>>(feaT, loc, pw, gidx, ffea, floc, out_noff, nlocp);
  knn_kernel<<<dim3(2048), dim3(256), 0, stream>>>(loc, nlocp, gidx2);
  nodefea_kernel<<<dim3(2048), dim3(256), 0, stream>>>(feaT, rw, gidx2, bnsc, bnsh, out_nf);
  interp_kernel<<<dim3(32, 32), dim3(256), 0, stream>>>(fea, loc, nlocp, out_nf, out);
}

// Round 8
// 551.456 us; speedup vs baseline: 1.1753x; 1.0746x over previous
//
#include <hip/hip_runtime.h>
#include <math.h>

// Problem constants
#define BB 32
#define NN 8192
#define CC 64
#define SS 64    // NUM_NODE
#define KK 64    // NSAMPLE

// Workspace layout (in floats)
#define WS_FIDX   0         // int[2048]
#define WS_FLOC   2048      // float[2048*3]
#define WS_FFEA   8192      // float[2048*64]
#define WS_GIDX   139264    // int[2048*64]
#define WS_NLOC   270336    // float[2048*3]
#define WS_GIDX2  276480    // int[2048*64]
#define WS_PART   407552    // float[512*4160]
#define WS_TOT    2537472   // float[4160]
#define WS_SCALE  2541632   // float[64]
#define WS_SHIFT  2541696   // float[64]

// ---------------------------------------------------------------------------
// Phase 1 (fused, 512 threads): blocks 0..31 = FPS, 32..4127 = transpose,
// 4128..4639 = cov. fps is latency-bound; transpose+cov fill the other CUs.
// ---------------------------------------------------------------------------

// FPS: 512 threads, 16 pts/thread in registers. Reduction carries only
// (value, index) through the 2-value butterfly (12 ds_bpermute/wave/iter);
// the winning point's coords come from the PROPOSER lane: the unique lane
// with bi == vi holds (bx,by,bz) in registers and writes them to a per-wave
// LDS slot. Scan picks winning wave w* and reads 3 broadcast floats.
// Selection semantics identical to reference: global argmax, min-index ties.
__device__ __forceinline__ void fps_body(int b, const float* __restrict__ loc,
                                         int* __restrict__ fidx,
                                         float (*wrv)[8], int (*wri)[8],
                                         float (*wcx)[8], float (*wcy)[8],
                                         float (*wcz)[8]) {
#pragma clang fp contract(off)
  __builtin_amdgcn_s_setprio(1);   // win issue arbitration vs bg waves
  int t = threadIdx.x;
  const float* lb = loc + (size_t)b * 3 * NN;
  float px[16], py[16], pz[16], dist[16];
#pragma unroll
  for (int k = 0; k < 16; k++) {
    int p = t + 512 * k;
    px[k] = lb[p];
    py[k] = lb[NN + p];
    pz[k] = lb[2 * NN + p];
    dist[k] = 1e10f;
  }
  int lane = t & 63, w = t >> 6;
  int far = 0;
  float cx = lb[0], cy = lb[NN], cz = lb[2 * NN];   // centroid 0 = point 0
  for (int it = 0; it < 64; it++) {
    if (t == 0) fidx[b * 64 + it] = far;
    float bv = -1.0f; int bi = 0;
    float bx = 0.f, by = 0.f, bz = 0.f;
#pragma unroll
    for (int k = 0; k < 16; k++) {
      float dx = px[k] - cx, dy = py[k] - cy, dz = pz[k] - cz;
      float d = (dx * dx + dy * dy) + dz * dz;
      float dm = dist[k];
      dm = d < dm ? d : dm;
      dist[k] = dm;
      if (dm > bv) { bv = dm; bi = t + 512 * k; bx = px[k]; by = py[k]; bz = pz[k]; }
    }
    // 2-value butterfly: all 64 lanes converge to wave winner (max val, min idx)
    float v = bv; int vi = bi;
#pragma unroll
    for (int off = 1; off < 64; off <<= 1) {
      float v2 = __shfl_xor(v, off, 64);
      int   i2 = __shfl_xor(vi, off, 64);
      if (v2 > v || (v2 == v && i2 < vi)) { v = v2; vi = i2; }
    }
    int par = it & 1;
    if (lane == 0) { wrv[par][w] = v; wri[par][w] = vi; }
    if (bi == vi) {  // unique proposer lane of this wave's winner
      wcx[par][w] = bx; wcy[par][w] = by; wcz[par][w] = bz;
    }
    __syncthreads();
    float gv = wrv[par][0]; int gi = wri[par][0]; int ws_ = 0;
#pragma unroll
    for (int w2 = 1; w2 < 8; w2++) {
      float v2 = wrv[par][w2]; int i2 = wri[par][w2];
      if (v2 > gv || (v2 == gv && i2 < gi)) { gv = v2; gi = i2; ws_ = w2; }
    }
    far = gi;                      // identical on every thread
    cx = wcx[par][ws_];            // 3 broadcast LDS reads — no global gather
    cy = wcy[par][ws_];
    cz = wcz[par][ws_];
  }
}

// Transpose body (512 thr, float4): fea[b][c][n] -> feaT[b][n][c]. For b>=16
// also writes the fea passthrough into out[b][c][n] (region starts at float
// 16777216, past feaT's [0,16777216) — no overlap).
__device__ __forceinline__ void transpose_body(int tb, const float* __restrict__ fea,
                                               float* __restrict__ feaT,
                                               float* __restrict__ out, float* tile) {
  int b = tb >> 7;            // 128 n-chunks per batch
  int n0 = (tb & 127) * 64;
  int t = threadIdx.x;
  const float* fb = fea + (size_t)b * (CC * NN);
  float* pb = out + (size_t)b * (128 * NN);
  bool pass = (b >= 16);
#pragma unroll
  for (int m = 0; m < 2; m++) {
    int q = m * 512 + t;             // float4 id, 1024 total
    int c = q >> 4, n4 = (q & 15) * 4;
    float4 v = *(const float4*)(fb + (size_t)c * NN + n0 + n4);
    tile[c * 65 + n4 + 0] = v.x;
    tile[c * 65 + n4 + 1] = v.y;
    tile[c * 65 + n4 + 2] = v.z;
    tile[c * 65 + n4 + 3] = v.w;
    if (pass) *(float4*)(pb + (size_t)c * NN + n0 + n4) = v;
  }
  __syncthreads();
  float* ob = feaT + ((size_t)b * NN + n0) * 64;
#pragma unroll
  for (int m = 0; m < 2; m++) {
    int q = m * 512 + t;
    int nl = q >> 4, c4 = (q & 15) * 4;
    float4 v;
    v.x = tile[(c4 + 0) * 65 + nl];
    v.y = tile[(c4 + 1) * 65 + nl];
    v.z = tile[(c4 + 2) * 65 + nl];
    v.w = tile[(c4 + 3) * 65 + nl];
    *(float4*)(ob + q * 4) = v;
  }
}

// Cov body (512 thr): float4 staging (same data/layout — bit-identical);
// compute waves 0-3 keep the EXACT summation order of the original kernel.
__device__ __forceinline__ void cov_body(int cb, const float* __restrict__ fea,
                                         float* __restrict__ part,
                                         float* Sf, float* red) {
  int t = threadIdx.x, w = t >> 6, lane = t & 63;
  int i = lane >> 3, j = lane & 7;
  float acc[8][8];
  float rs[8];
#pragma unroll
  for (int r = 0; r < 8; r++) {
    rs[r] = 0.f;
#pragma unroll
    for (int r2 = 0; r2 < 8; r2++) acc[r][r2] = 0.f;
  }
  for (int q = 0; q < 4; q++) {
    int chunk = cb * 4 + q;
    int p0 = chunk * 128;
    int b = p0 >> 13, n0 = p0 & 8191;
    __syncthreads();
    const float* fb = fea + (size_t)b * (CC * NN) + n0;
#pragma unroll
    for (int m = 0; m < 4; m++) {
      int q4 = m * 512 + t;              // 2048 float4 = 64c x 128pt
      int c = q4 >> 5, p4 = (q4 & 31) * 4;
      float4 v = *(const float4*)(fb + (size_t)c * NN + p4);
      Sf[c * 133 + p4 + 0] = v.x;
      Sf[c * 133 + p4 + 1] = v.y;
      Sf[c * 133 + p4 + 2] = v.z;
      Sf[c * 133 + p4 + 3] = v.w;
    }
    __syncthreads();
    if (w < 4) {
      for (int pt = w * 32; pt < w * 32 + 32; pt++) {
        float a[8], bv[8];
#pragma unroll
        for (int r = 0; r < 8; r++) {
          a[r] = Sf[(8 * i + r) * 133 + pt];
          bv[r] = Sf[(8 * j + r) * 133 + pt];
        }
#pragma unroll
        for (int r = 0; r < 8; r++) {
          rs[r] += a[r];
#pragma unroll
          for (int r2 = 0; r2 < 8; r2++) acc[r][r2] = fmaf(a[r], bv[r2], acc[r][r2]);
        }
      }
    }
  }
  for (int ww = 0; ww < 4; ww++) {
    if (w == ww) {
#pragma unroll
      for (int r = 0; r < 8; r++) {
#pragma unroll
        for (int r2 = 0; r2 < 8; r2++) {
          int idx = (8 * i + r) * 64 + 8 * j + r2;
          if (ww == 0) red[idx] = acc[r][r2]; else red[idx] += acc[r][r2];
        }
        if (j == 0) {
          int ridx = 4096 + 8 * i + r;
          if (ww == 0) red[ridx] = rs[r]; else red[ridx] += rs[r];
        }
      }
    }
    __syncthreads();
  }
  float* pb = part + (size_t)cb * 4160;
  for (int idx = t; idx < 4160; idx += 512) pb[idx] = red[idx];
}

__global__ __launch_bounds__(512, 1) void phase1_kernel(const float* __restrict__ fea,
                                                        const float* __restrict__ loc,
                                                        float* __restrict__ feaT,
                                                        float* __restrict__ out,
                                                        int* __restrict__ fidx,
                                                        float* __restrict__ part) {
  __shared__ __align__(16) char smem[50688];   // union: transpose 16640B, cov 50688B
  __shared__ float wrv[2][8], wcx[2][8], wcy[2][8], wcz[2][8];
  __shared__ int wri[2][8];
  int blk = blockIdx.x;
  if (blk < 32) {
    fps_body(blk, loc, fidx, wrv, wri, wcx, wcy, wcz);
  } else if (blk < 4128) {
    transpose_body(blk - 32, fea, feaT, out, (float*)smem);
  } else {
    cov_body(blk - 4128, fea, part, (float*)smem, (float*)(smem + 34048));
  }
}

// ---------------------------------------------------------------------------
// Phase 2 (fused): blocks 0..16 = covreduce, 17..528 = gather (4 bs per block).
// ---------------------------------------------------------------------------
__global__ __launch_bounds__(256) void phase2_kernel(const float* __restrict__ part,
                                                     float* __restrict__ tot,
                                                     const float* __restrict__ loc,
                                                     const float* __restrict__ fea,
                                                     const int* __restrict__ fidx,
                                                     float* __restrict__ floc,
                                                     float* __restrict__ ffea) {
  int blk = blockIdx.x, t = threadIdx.x;
  if (blk < 17) {
    int e = blk * 256 + t;
    if (e >= 4160) return;
    float s = 0.f;
    for (int b2 = 0; b2 < 512; b2++) s += part[(size_t)b2 * 4160 + e];
    tot[e] = s;
  } else {
    int bs = (blk - 17) * 4 + (t >> 6);
    int c = t & 63;
    int b = bs >> 6;
    int g = fidx[bs];
    ffea[bs * 64 + c] = fea[(size_t)b * (CC * NN) + (size_t)c * NN + g];
    if (c < 3) floc[bs * 3 + c] = loc[(size_t)b * (3 * NN) + (size_t)c * NN + g];
  }
}

// ---------------------------------------------------------------------------
// Phase 3 (fused): blocks 0..511 = ball query (radius, EARLY EXIT),
// block 512 = bnstats.
// ---------------------------------------------------------------------------
__global__ __launch_bounds__(256) void phase3_kernel(const float* __restrict__ loc,
                                                     const float* __restrict__ floc,
                                                     int* __restrict__ gidx,
                                                     const float* __restrict__ tot,
                                                     const float* __restrict__ rw,
                                                     const float* __restrict__ rb,
                                                     const float* __restrict__ gam,
                                                     const float* __restrict__ bet,
                                                     float* __restrict__ bnsc,
                                                     float* __restrict__ bnsh) {
#pragma clang fp contract(off)
  int blk = blockIdx.x;
  if (blk < 512) {
    int w = threadIdx.x >> 6, lane = threadIdx.x & 63;
    int bs = blk * 4 + w, b = bs >> 6;
    const float* lb = loc + (size_t)b * 3 * NN;
    float ax = floc[bs * 3], ay = floc[bs * 3 + 1], az = floc[bs * 3 + 2];
    float A = (ax * ax + ay * ay) + az * az;
    int count = 0, firsth = -1;
    for (int ch = 0; ch < 128 && count < 64; ch++) {
      int p = ch * 64 + lane;
      float bx = lb[p], by = lb[NN + p], bz = lb[2 * NN + p];
      float Bn = (bx * bx + by * by) + bz * bz;
      float dot = fmaf(az, bz, fmaf(ay, by, ax * bx));
      float sqr = (A + Bn) - 2.0f * dot;
      bool hit = !(sqr > 0.09f);
      unsigned long long m = __ballot(hit);
      if (m) {
        if (firsth < 0) firsth = ch * 64 + (int)__ffsll(m) - 1;
        int pos = count + (int)__popcll(m & ((1ull << lane) - 1ull));
        if (hit && pos < 64) gidx[bs * 64 + pos] = p;
        count += (int)__popcll(m);
      }
    }
    if (count < 64 && lane >= count) gidx[bs * 64 + lane] = firsth;
  } else {
    int o = threadIdx.x;
    if (o >= 64) return;
    const float invM = 1.0f / 262144.0f;
    float mu = 0.f;
    for (int c = 0; c < 64; c++) mu += rw[o * 64 + c] * (tot[4096 + c] * invM);
    float exx = 0.f;
    for (int c = 0; c < 64; c++) {
      const float* row = tot + c * 64;
      float p = 0.f;
      for (int c2 = 0; c2 < 64; c2++) p += rw[o * 64 + c2] * row[c2];
      exx += rw[o * 64 + c] * p;
    }
    exx *= invM;
    float var = exx - mu * mu;
    float mean = mu + rb[o];
    float sc = gam[o] / sqrtf(var + 1e-5f);
    bnsc[o] = sc;
    bnsh[o] = bet[o] - mean * sc;
  }
}

// ---------------------------------------------------------------------------
// seman/node_offset/node_loc. One wave per (b,s), lane = k.
// ---------------------------------------------------------------------------
__global__ __launch_bounds__(64) void seman_kernel(const float* __restrict__ feaT,
                                                   const float* __restrict__ loc,
                                                   const float* __restrict__ pw,
                                                   const int* __restrict__ gidx,
                                                   const float* __restrict__ ffea,
                                                   const float* __restrict__ floc,
                                                   float* __restrict__ out_noff,
                                                   float* __restrict__ nloc) {
  int bs = blockIdx.x, b = bs >> 6, s = bs & 63, k = threadIdx.x;
  __shared__ float sf[64];
  __shared__ float spw[192];
  __shared__ float sl[3];
  sf[k] = ffea[bs * 64 + k];
  spw[k] = pw[k]; spw[64 + k] = pw[64 + k]; spw[128 + k] = pw[128 + k];
  if (k < 3) sl[k] = floc[bs * 3 + k];
  __syncthreads();
  int g = gidx[bs * 64 + k];
  const float* fT = feaT + ((size_t)b * NN + g) * 64;
  float a0 = 0.f, a1 = 0.f, a2 = 0.f;
#pragma unroll
  for (int c4 = 0; c4 < 16; c4++) {
    float4 f = *(const float4*)(fT + 4 * c4);
    int c = 4 * c4;
    float g0 = f.x - sf[c + 0];
    a0 = fmaf(spw[c + 0], g0, a0); a1 = fmaf(spw[64 + c + 0], g0, a1); a2 = fmaf(spw[128 + c + 0], g0, a2);
    float g1 = f.y - sf[c + 1];
    a0 = fmaf(spw[c + 1], g1, a0); a1 = fmaf(spw[64 + c + 1], g1, a1); a2 = fmaf(spw[128 + c + 1], g1, a2);
    float g2 = f.z - sf[c + 2];
    a0 = fmaf(spw[c + 2], g2, a0); a1 = fmaf(spw[64 + c + 2], g2, a1); a2 = fmaf(spw[128 + c + 2], g2, a2);
    float g3 = f.w - sf[c + 3];
    a0 = fmaf(spw[c + 3], g3, a0); a1 = fmaf(spw[64 + c + 3], g3, a1); a2 = fmaf(spw[128 + c + 3], g3, a2);
  }
  const float* lb = loc + (size_t)b * 3 * NN;
  float c0 = tanhf(a0) * (lb[g] - sl[0]);
  float c1 = tanhf(a1) * (lb[NN + g] - sl[1]);
  float c2 = tanhf(a2) * (lb[2 * NN + g] - sl[2]);
#pragma unroll
  for (int off = 32; off; off >>= 1) {
    c0 += __shfl_xor(c0, off, 64);
    c1 += __shfl_xor(c1, off, 64);
    c2 += __shfl_xor(c2, off, 64);
  }
  if (k == 0) {
    float m0 = c0 * (1.0f / 64), m1 = c1 * (1.0f / 64), m2 = c2 * (1.0f / 64);
    out_noff[b * 192 + s] = m0;
    out_noff[b * 192 + 64 + s] = m1;
    out_noff[b * 192 + 128 + s] = m2;
    nloc[bs * 3 + 0] = sl[0] + m0;
    nloc[bs * 3 + 1] = sl[1] + m1;
    nloc[bs * 3 + 2] = sl[2] + m2;
  }
}

// ---------------------------------------------------------------------------
// kNN-64 radix select, keys in registers only (~17.5KB LDS).
// ---------------------------------------------------------------------------
__global__ __launch_bounds__(256) void knn_kernel(const float* __restrict__ loc,
                                                  const float* __restrict__ nloc,
                                                  int* __restrict__ gidx2) {
#pragma clang fp contract(off)
  int bs = blockIdx.x, b = bs >> 6, t = threadIdx.x;
  int lane = t & 63, w = t >> 6;
  const float* lb = loc + (size_t)b * 3 * NN;
  float ax = nloc[bs * 3], ay = nloc[bs * 3 + 1], az = nloc[bs * 3 + 2];
  float A = (ax * ax + ay * ay) + az * az;
  __shared__ unsigned hist[4096];
  __shared__ unsigned partl[256];
  __shared__ unsigned wrk[4];
  __shared__ int wrp[4];
  __shared__ unsigned selk;
  __shared__ int selp;
  __shared__ int sP, sC0, nOut;
  for (int m = 0; m < 16; m++) hist[m * 256 + t] = 0u;
  if (t == 0) nOut = 0;
  __syncthreads();
  unsigned mykey[32];
#pragma unroll
  for (int k = 0; k < 32; k++) {
    int p = t + 256 * k;
    float bx = lb[p], by = lb[NN + p], bz = lb[2 * NN + p];
    float Bn = (bx * bx + by * by) + bz * bz;
    float dot = fmaf(az, bz, fmaf(ay, by, ax * bx));
    float d = (A + Bn) - 2.0f * dot;
    unsigned kb = __float_as_uint(d);
    kb = (kb & 0x80000000u) ? ~kb : (kb | 0x80000000u);   // monotonic transform
    mykey[k] = kb;
    atomicAdd(&hist[kb >> 20], 1u);
  }
  __syncthreads();
  unsigned ps = 0;
#pragma unroll
  for (int m = 0; m < 16; m++) ps += hist[t * 16 + m];
  partl[t] = ps;
  __syncthreads();
  if (t == 0) {
    int cum = 0, seg = 0;
    for (int t2 = 0; t2 < 256; t2++) {
      if (cum + (int)partl[t2] >= 64) { seg = t2; break; }
      cum += (int)partl[t2];
    }
    int P = seg * 16;
    for (;; P++) {
      if (cum + (int)hist[P] >= 64) break;
      cum += (int)hist[P];
    }
    sP = P; sC0 = cum;
  }
  __syncthreads();
  int P = sP, C0 = sC0;
#pragma unroll
  for (int k = 0; k < 32; k++) {
    if ((int)(mykey[k] >> 20) < P) {
      int pos = atomicAdd(&nOut, 1);
      gidx2[bs * 64 + pos] = t + 256 * k;
    }
  }
  int R = 64 - C0;
  unsigned lastk = 0u; int lastp = -1;
  for (int r = 0; r < R; r++) {
    unsigned bk = 0xFFFFFFFFu; int bp = 0x7FFFFFFF;
#pragma unroll
    for (int k = 0; k < 32; k++) {
      unsigned kk = mykey[k];
      if ((int)(kk >> 20) == P) {
        int p = t + 256 * k;
        bool gt = (kk > lastk) || (kk == lastk && p > lastp);
        if (gt && (kk < bk || (kk == bk && p < bp))) { bk = kk; bp = p; }
      }
    }
#pragma unroll
    for (int off = 1; off < 64; off <<= 1) {
      unsigned k2 = __shfl_xor(bk, off, 64);
      int p2 = __shfl_xor(bp, off, 64);
      if (k2 < bk || (k2 == bk && p2 < bp)) { bk = k2; bp = p2; }
    }
    if (lane == 0) { wrk[w] = bk; wrp[w] = bp; }
    __syncthreads();
    if (t == 0) {
      unsigned fk = wrk[0]; int fp = wrp[0];
#pragma unroll
      for (int w2 = 1; w2 < 4; w2++) {
        unsigned k2 = wrk[w2]; int p2 = wrp[w2];
        if (k2 < fk || (k2 == fk && p2 < fp)) { fk = k2; fp = p2; }
      }
      gidx2[bs * 64 + C0 + r] = fp;
      selk = fk; selp = fp;
    }
    __syncthreads();
    lastk = selk; lastp = selp;
  }
}

// ---------------------------------------------------------------------------
// node_fea = max_k relu(BN(W . fea[gidx2])). Gather via feaT (coalesced).
// ---------------------------------------------------------------------------
__global__ __launch_bounds__(256) void nodefea_kernel(const float* __restrict__ feaT,
                                                      const float* __restrict__ rw,
                                                      const int* __restrict__ gidx2,
                                                      const float* __restrict__ bnsc,
                                                      const float* __restrict__ bnsh,
                                                      float* __restrict__ out_nf) {
  __shared__ __align__(16) float Lf[4096];  // [k][c]
  __shared__ float Lw[4096];                // [c][o] = rw[o][c]
  __shared__ int Lg[64];
  __shared__ float red[256];
  int bs = blockIdx.x, b = bs >> 6, s = bs & 63, t = threadIdx.x;
  if (t < 64) Lg[t] = gidx2[bs * 64 + t];
  __syncthreads();
#pragma unroll
  for (int m = 0; m < 4; m++) {
    int idx4 = m * 256 + t;               // 1024 float4s
    int k = idx4 >> 4, c4 = idx4 & 15;
    float4 f = *(const float4*)(feaT + ((size_t)b * NN + Lg[k]) * 64 + 4 * c4);
    *(float4*)&Lf[idx4 * 4] = f;
  }
  for (int m = 0; m < 16; m++) {
    int idx = m * 256 + t;
    Lw[idx] = rw[(idx & 63) * 64 + (idx >> 6)];
  }
  __syncthreads();
  int o = t & 63, wq = t >> 6;
  float wreg[64];
#pragma unroll
  for (int c = 0; c < 64; c++) wreg[c] = Lw[c * 64 + o];
  float sc = bnsc[o], sh = bnsh[o];
  float mx = -1e30f;
  for (int k = wq * 16; k < wq * 16 + 16; k++) {
    float raw = 0.f;
#pragma unroll
    for (int c4 = 0; c4 < 16; c4++) {
      float4 lf = *(const float4*)&Lf[k * 64 + c4 * 4];
      raw = fmaf(wreg[4 * c4 + 0], lf.x, raw);
      raw = fmaf(wreg[4 * c4 + 1], lf.y, raw);
      raw = fmaf(wreg[4 * c4 + 2], lf.z, raw);
      raw = fmaf(wreg[4 * c4 + 3], lf.w, raw);
    }
    float v = raw * sc + sh;
    v = v > 0.f ? v : 0.f;
    mx = v > mx ? v : mx;
  }
  red[wq * 64 + o] = mx;
  __syncthreads();
  if (t < 64) {
    float m0 = red[t], m1 = red[64 + t], m2 = red[128 + t], m3 = red[192 + t];
    float ma = m0 > m1 ? m0 : m1;
    float mb = m2 > m3 ? m2 : m3;
    float m = ma > mb ? ma : mb;
    out_nf[b * 4096 + t * 64 + s] = m;   // node_fea[b][o=t][s]
  }
}

// ---------------------------------------------------------------------------
// 3-NN inverse-distance interpolation. node_fea staged in LDS. Passthrough
// only for b<16 (b>=16 was written by transpose in phase1).
// ---------------------------------------------------------------------------
__global__ __launch_bounds__(256) void interp_kernel(const float* __restrict__ fea,
                                                     const float* __restrict__ loc,
                                                     const float* __restrict__ nloc,
                                                     const float* __restrict__ nf,
                                                     float* __restrict__ out) {
#pragma clang fp contract(off)
  int b = blockIdx.y;
  int t = threadIdx.x;
  int n = blockIdx.x * 256 + t;
  __shared__ float snl[192];
  __shared__ float sB[64];
  __shared__ float snf[4096];   // nf[b] staged (16KB)
  if (t < 192) snl[t] = nloc[b * 192 + t];
  {
    const float* nfb = nf + b * 4096;
#pragma unroll
    for (int m = 0; m < 16; m++) snf[m * 256 + t] = nfb[m * 256 + t];
  }
  __syncthreads();
  if (t < 64) {
    float x = snl[t * 3], y = snl[t * 3 + 1], z = snl[t * 3 + 2];
    sB[t] = (x * x + y * y) + z * z;
  }
  __syncthreads();
  const float* lb = loc + (size_t)b * 3 * NN;
  float px = lb[n], py = lb[NN + n], pz = lb[2 * NN + n];
  float A = (px * px + py * py) + pz * pz;
  float d0 = 1e30f, d1 = 1e30f, d2 = 1e30f;
  int i0 = 0, i1 = 0, i2 = 0;
  for (int s = 0; s < 64; s++) {
    float dot = fmaf(pz, snl[s * 3 + 2], fmaf(py, snl[s * 3 + 1], px * snl[s * 3]));
    float d = (A + sB[s]) - 2.0f * dot;
    if (d < d0) { d2 = d1; i2 = i1; d1 = d0; i1 = i0; d0 = d; i0 = s; }
    else if (d < d1) { d2 = d1; i2 = i1; d1 = d; i1 = s; }
    else if (d < d2) { d2 = d; i2 = s; }
  }
  d0 = d0 > 1e-10f ? d0 : 1e-10f;
  d1 = d1 > 1e-10f ? d1 : 1e-10f;
  d2 = d2 > 1e-10f ? d2 : 1e-10f;
  float r0 = 1.0f / d0, r1 = 1.0f / d1, r2 = 1.0f / d2;
  float rsum = (r0 + r1) + r2;
  float w0 = r0 / rsum, w1 = r1 / rsum, w2 = r2 / rsum;
  const float* fb = fea + (size_t)b * (CC * NN);
  float* ob = out + (size_t)b * (128 * NN);
  bool pass = (b < 16);
  for (int o = 0; o < 64; o++) {
    if (pass) ob[(size_t)o * NN + n] = fb[(size_t)o * NN + n];
    float ip = (snf[o * 64 + i0] * w0 + snf[o * 64 + i1] * w1) + snf[o * 64 + i2] * w2;
    ob[(size_t)(64 + o) * NN + n] = ip;
  }
}

// ---------------------------------------------------------------------------
extern "C" void kernel_launch(void* const* d_in, const int* in_sizes, int n_in,
                              void* d_out, int out_size, void* d_ws, size_t ws_size,
                              hipStream_t stream) {
  (void)in_sizes; (void)n_in; (void)out_size; (void)ws_size;
  const float* fea = (const float*)d_in[0];
  const float* loc = (const float*)d_in[1];
  const float* pw  = (const float*)d_in[2];
  const float* rw  = (const float*)d_in[3];
  const float* rb  = (const float*)d_in[4];
  const float* gam = (const float*)d_in[5];
  const float* bet = (const float*)d_in[6];
  float* out = (float*)d_out;
  float* ws = (float*)d_ws;

  int*   fidx  = (int*)(ws + WS_FIDX);
  float* floc  = ws + WS_FLOC;
  float* ffea  = ws + WS_FFEA;
  int*   gidx  = (int*)(ws + WS_GIDX);
  float* nlocp = ws + WS_NLOC;
  int*   gidx2 = (int*)(ws + WS_GIDX2);
  float* part  = ws + WS_PART;
  float* tot   = ws + WS_TOT;
  float* bnsc  = ws + WS_SCALE;
  float* bnsh  = ws + WS_SHIFT;

  float* feaT     = out;             // 64 MB scratch (batches 0-15 region)
  float* out_nf   = out + 33554432;  // node_fea   (B,64,64,1)
  float* out_noff = out + 33685504;  // node_offset(B,3,64)

  // Phase 1: fps (32) + transpose/passthrough (4096) + cov (512) concurrent.
  phase1_kernel<<<dim3(4640), dim3(512), 0, stream>>>(fea, loc, feaT, out, fidx, part);
  // Phase 2: covreduce (17) + fpoint gather (512).
  phase2_kernel<<<dim3(529), dim3(256), 0, stream>>>(part, tot, loc, fea, fidx, floc, ffea);
  // Phase 3: ball query w/ early exit (512) + bnstats (1).
  phase3_kernel<<<dim3(513), dim3(256), 0, stream>>>(loc, floc, gidx, tot, rw, rb, gam, bet, bnsc, bnsh);
  seman_kernel<<<dim3(2048), dim3(64), 0, stream>>>(feaT, loc, pw, gidx, ffea, floc, out_noff, nlocp);
  knn_kernel<<<dim3(2048), dim3(256), 0, stream>>>(loc, nlocp, gidx2);
  nodefea_kernel<<<dim3(2048), dim3(256), 0, stream>>>(feaT, rw, gidx2, bnsc, bnsh, out_nf);
  interp_kernel<<<dim3(32, 32), dim3(256), 0, stream>>>(fea, loc, nlocp, out_nf, out);
}